// Round 6
// baseline (493.369 us; speedup 1.0000x reference)
//
#include <hip/hip_runtime.h>

#define HH 192
#define WW 384
#define CC 16
#define OH 184
#define OW 376
#define NTAP 25
#define TILE 64

// Kernel A: S[b][y][x] = sum_c volume[...]; first nW threads also transpose weights:
// w_t[tn][kk][c][j] = w_off[kk][c][4*tn+j]
__global__ void prep_kernel(const float* __restrict__ vol, float* __restrict__ S,
                            const float* __restrict__ w_off, float4* __restrict__ w_t,
                            int nS, int nW) {
    int idx = blockIdx.x * 256 + threadIdx.x;
    if (idx < nS) {
        const float4* p = reinterpret_cast<const float4*>(vol + (size_t)idx * CC);
        float4 a = p[0], b = p[1], c = p[2], d = p[3];
        S[idx] = ((a.x + a.y) + (a.z + a.w)) + ((b.x + b.y) + (b.z + b.w))
               + ((c.x + c.y) + (c.z + c.w)) + ((d.x + d.y) + (d.z + d.w));
    }
    if (idx < nW) {
        int kk = (idx >> 4) % 25;
        int tn = idx / (25 * 16);
        w_t[idx] = *reinterpret_cast<const float4*>(w_off + ((idx & 15) + kk * 16) * 100 + 4 * tn);
    }
}

// 16 FMAs: acc.{x,y,z,w} += dot(4-channel v, weight quads w0..w3)
#define DOT4Q(acc, v, w0, w1, w2, w3) do {                                   \
    acc.x = fmaf(v.x, w0.x, acc.x); acc.x = fmaf(v.y, w1.x, acc.x);          \
    acc.x = fmaf(v.z, w2.x, acc.x); acc.x = fmaf(v.w, w3.x, acc.x);          \
    acc.y = fmaf(v.x, w0.y, acc.y); acc.y = fmaf(v.y, w1.y, acc.y);          \
    acc.y = fmaf(v.z, w2.y, acc.y); acc.y = fmaf(v.w, w3.y, acc.y);          \
    acc.z = fmaf(v.x, w0.z, acc.z); acc.z = fmaf(v.y, w1.z, acc.z);          \
    acc.z = fmaf(v.z, w2.z, acc.z); acc.z = fmaf(v.w, w3.z, acc.z);          \
    acc.w = fmaf(v.x, w0.w, acc.w); acc.w = fmaf(v.y, w1.w, acc.w);          \
    acc.w = fmaf(v.z, w2.w, acc.w); acc.w = fmaf(v.w, w3.w, acc.w);          \
} while (0)

// Fused dilated 5x5 offset conv + bilinear sampling.
// Block: 320 thr = 5 waves; wave wid computes taps tn = 5*wid + tq (tq=0..4) for
// 2 same-parity output rows (oy0 = p+4*gy, oy0+2) x 64 px. All 25 taps per block:
// volume tile staged ONCE, each ds_read_b128 pair feeds 160 FMAs, and the block
// writes all 25 taps -> contiguous 100B output runs (no write amplification).
__global__ __launch_bounds__(320) void dconv_kernel(
    const float* __restrict__ vol, const float* __restrict__ w_t,
    const float* __restrict__ b_off, const float* __restrict__ S,
    float* __restrict__ out)
{
    __shared__ float4 lds[4][6][73];   // [ch-quad][row][col]  28,032 B

    const int tid  = threadIdx.x;
    const int lane = tid & 63;
    const int wid  = tid >> 6;          // 0..4  (tap row ky)
    const int z    = blockIdx.z;        // b*2+p
    const int p    = z & 1;
    const int b    = z >> 1;
    const int gy   = blockIdx.y;        // 0..45
    const int oy0  = p + 4 * gy;
    const int ox0  = blockIdx.x * TILE;

    // stage 6 rows: global row = oy0 + 2t (t=0..5), cols ox0..ox0+71 (clamped), 16 ch.
    // colr fastest over tid -> contiguous ds_write_b128, conflict-free.
    {
        const float* __restrict__ vb = vol + (size_t)((b * HH + oy0) * WW) * CC;
        for (int i = tid; i < 6 * 72 * 4; i += 320) {
            const int colr = i % 72;
            const int rem  = i / 72;
            const int t    = rem % 6;
            const int q    = rem / 6;
            int colg = ox0 + colr; if (colg > WW - 1) colg = WW - 1;
            lds[q][t][colr] = *reinterpret_cast<const float4*>(
                vb + (size_t)(2 * t * WW + colg) * CC + 4 * q);
        }
    }
    __syncthreads();

    // per-wave tap base pointers (wave-uniform -> scalar weight loads)
    const float4* __restrict__ w4 = reinterpret_cast<const float4*>(w_t);
    const float4* wtap[5];
    #pragma unroll
    for (int tq = 0; tq < 5; ++tq)
        wtap[tq] = w4 + (size_t)(5 * wid + tq) * 400;   // 400 float4 per tap

    float4 acc[5][2];
    #pragma unroll
    for (int tq = 0; tq < 5; ++tq) {
        const float4 bo = *reinterpret_cast<const float4*>(b_off + 4 * (5 * wid + tq));
        acc[tq][0] = bo; acc[tq][1] = bo;
    }

    #pragma unroll 1
    for (int r = 0; r < 5; ++r) {
        #pragma unroll 1
        for (int kx = 0; kx < 5; ++kx) {
            const int cl = lane + 2 * kx;
            const int wo = (r * 5 + kx) * 16;      // float4 offset within tap block
            #pragma unroll
            for (int cq = 0; cq < 4; ++cq) {
                const float4 v0 = lds[cq][r + 0][cl];
                const float4 v1 = lds[cq][r + 1][cl];
                #pragma unroll
                for (int tq = 0; tq < 5; ++tq) {
                    const float4* __restrict__ W = wtap[tq] + wo + 4 * cq;
                    const float4 w0 = W[0], w1 = W[1], w2 = W[2], w3 = W[3];
                    DOT4Q(acc[tq][0], v0, w0, w1, w2, w3);
                    DOT4Q(acc[tq][1], v1, w0, w1, w2, w3);
                }
            }
        }
    }

    // sampling epilogue: lane's pixel; 5 taps x 2 rows x 2 groups
    const int ox = ox0 + lane;
    if (ox < OW) {
        const float* __restrict__ Sb = S + b * HH * WW;
        const float kv = (float)(2 * wid - 4);          // kyt = tn/5 = wid
        #pragma unroll
        for (int tq = 0; tq < 5; ++tq) {
            const int tn = 5 * wid + tq;
            const float ku = (float)(2 * tq - 4);       // kxt = tn%5 = tq
            #pragma unroll
            for (int j = 0; j < 2; ++j) {
                const int oy = oy0 + 2 * j;
                const float4 a = acc[tq][j];
                const float byv = (float)(4 + oy);
                #pragma unroll
                for (int g = 0; g < 2; ++g) {
                    const float dy = g == 0 ? a.x : a.y;
                    const float dx = g == 0 ? a.z : a.w;
                    const float rx = kv + dy;     // pairs with W axis (reference quirk)
                    const float ry = ku + dx;     // pairs with H axis
                    int x0 = (int)rx;             // trunc == astype(int32)
                    int x1 = x0 + 1;
                    int y0 = (int)ry;
                    int y1 = y0 + 1;
                    int x0c = min(max(x0, 0), WW - 1);
                    int x1c = min(max(x1, 0), WW - 1);
                    int y0c = min(max(y0, 0), HH - 1);
                    int y1c = min(max(y1, 0), HH - 1);
                    const float fx0 = (float)x0c, fx1 = (float)x1c;
                    const float fy0 = (float)y0c, fy1 = (float)y1c;
                    const float w0v = (fy1 - ry)  * (fx1 - rx);
                    const float w1v = (fy1 - byv) * (rx - fx0);
                    const float w2v = (ry - fy0)  * (fx1 - rx);
                    const float w3v = (ry - fy0)  * (rx - fx0);
                    const float s00 = Sb[y0c * WW + x0c];
                    const float s01 = Sb[y0c * WW + x1c];
                    const float s10 = Sb[y1c * WW + x0c];
                    const float s11 = Sb[y1c * WW + x1c];
                    out[(size_t)(((b * 2 + g) * OH + oy) * OW + ox) * NTAP + tn]
                        = w0v * s00 + w1v * s01 + w2v * s10 + w3v * s11;
                }
            }
        }
    }
}

extern "C" void kernel_launch(void* const* d_in, const int* in_sizes, int n_in,
                              void* d_out, int out_size, void* d_ws, size_t ws_size,
                              hipStream_t stream) {
    const float* vol   = (const float*)d_in[0];
    const float* w_off = (const float*)d_in[1];
    const float* b_off = (const float*)d_in[2];
    float* out = (float*)d_out;

    float* S   = (float*)d_ws;                                   // 576 KiB
    float* w_t = (float*)((char*)d_ws + 2 * HH * WW * 4);        // 160 KB

    const int nS = 2 * HH * WW;
    const int nW = NTAP * 25 * 16;
    prep_kernel<<<(nS + 255) / 256, 256, 0, stream>>>(vol, S, w_off, (float4*)w_t, nS, nW);

    dim3 grid((OW + TILE - 1) / TILE, 46, 4);   // 6 x 46 x 4 = 1104 blocks
    dconv_kernel<<<grid, 320, 0, stream>>>(vol, w_t, b_off, S, out);
}

// Round 8
// 213.407 us; speedup vs baseline: 2.3119x; 2.3119x over previous
//
#include <hip/hip_runtime.h>

#define HH 192
#define WW 384
#define CC 16
#define OH 184
#define OW 376
#define NTAP 25
#define TILE 64

// Kernel A: S[b][y][x] = sum_c volume[...]; first nW threads also transpose weights:
// w_t[tn][kk][c][j] = w_off[kk][c][4*tn+j]
__global__ void prep_kernel(const float* __restrict__ vol, float* __restrict__ S,
                            const float* __restrict__ w_off, float4* __restrict__ w_t,
                            int nS, int nW) {
    int idx = blockIdx.x * 256 + threadIdx.x;
    if (idx < nS) {
        const float4* p = reinterpret_cast<const float4*>(vol + (size_t)idx * CC);
        float4 a = p[0], b = p[1], c = p[2], d = p[3];
        S[idx] = ((a.x + a.y) + (a.z + a.w)) + ((b.x + b.y) + (b.z + b.w))
               + ((c.x + c.y) + (c.z + c.w)) + ((d.x + d.y) + (d.z + d.w));
    }
    if (idx < nW) {
        int kk = (idx >> 4) % 25;
        int tn = idx / (25 * 16);
        w_t[idx] = *reinterpret_cast<const float4*>(w_off + ((idx & 15) + kk * 16) * 100 + 4 * tn);
    }
}

// 16 FMAs: acc.{x,y,z,w} += dot(4-channel v, weight quads w0..w3)
#define DOT4Q(acc, v, w0, w1, w2, w3) do {                                   \
    acc.x = fmaf(v.x, w0.x, acc.x); acc.x = fmaf(v.y, w1.x, acc.x);          \
    acc.x = fmaf(v.z, w2.x, acc.x); acc.x = fmaf(v.w, w3.x, acc.x);          \
    acc.y = fmaf(v.x, w0.y, acc.y); acc.y = fmaf(v.y, w1.y, acc.y);          \
    acc.y = fmaf(v.z, w2.y, acc.y); acc.y = fmaf(v.w, w3.y, acc.y);          \
    acc.z = fmaf(v.x, w0.z, acc.z); acc.z = fmaf(v.y, w1.z, acc.z);          \
    acc.z = fmaf(v.z, w2.z, acc.z); acc.z = fmaf(v.w, w3.z, acc.z);          \
    acc.w = fmaf(v.x, w0.w, acc.w); acc.w = fmaf(v.y, w1.w, acc.w);          \
    acc.w = fmaf(v.z, w2.w, acc.w); acc.w = fmaf(v.w, w3.w, acc.w);          \
} while (0)

// Fused dilated 5x5 offset conv + bilinear sampling.
// Block: 320 thr = 5 waves; wave wid owns taps tnb..tnb+4 (tnb = readfirstlane(5*wid)
// -> WAVE-UNIFORM -> all weights via scalar s_load, zero vL1 traffic).
// 2 same-parity output rows (oy0 = p+4*gy, oy0+2) x 64 px; all 25 taps per block:
// volume staged once; per (r,kx): 8 ds_read_b128 feed 3200 block-FMAs (LDS ratio 0.3);
// block writes all 25 taps -> contiguous 100B runs.
__global__ __launch_bounds__(320) void dconv_kernel(
    const float* __restrict__ vol, const float* __restrict__ w_t,
    const float* __restrict__ b_off, const float* __restrict__ S,
    float* __restrict__ out)
{
    __shared__ float4 lds[4][6][73];   // [ch-quad][row][col]  28,032 B

    const int tid  = threadIdx.x;
    const int lane = tid & 63;
    const int wid  = tid >> 6;          // 0..4  (tap row ky)
    const int z    = blockIdx.z;        // b*2+p
    const int p    = z & 1;
    const int b    = z >> 1;
    const int gy   = blockIdx.y;        // 0..45
    const int oy0  = p + 4 * gy;
    const int ox0  = blockIdx.x * TILE;
    const int tnb  = __builtin_amdgcn_readfirstlane(5 * wid);   // base tap, uniform

    // stage 6 rows: global row = oy0 + 2t (t=0..5), cols ox0..ox0+71 (clamped), 16 ch
    {
        const float* __restrict__ vb = vol + (size_t)((b * HH + oy0) * WW) * CC;
        for (int i = tid; i < 6 * 72 * 4; i += 320) {
            const int colr = i % 72;
            const int rem  = i / 72;
            const int t    = rem % 6;
            const int q    = rem / 6;
            int colg = ox0 + colr; if (colg > WW - 1) colg = WW - 1;
            lds[q][t][colr] = *reinterpret_cast<const float4*>(
                vb + (size_t)(2 * t * WW + colg) * CC + 4 * q);
        }
    }
    __syncthreads();

    const float4* __restrict__ wbase =
        reinterpret_cast<const float4*>(w_t) + (size_t)tnb * 400;  // uniform

    float4 acc[5][2];
    #pragma unroll
    for (int tq = 0; tq < 5; ++tq) {
        const float4 bo = *reinterpret_cast<const float4*>(b_off + 4 * (tnb + tq));
        acc[tq][0] = bo; acc[tq][1] = bo;
    }

    #pragma unroll 1
    for (int r = 0; r < 5; ++r) {
        #pragma unroll 1
        for (int kx = 0; kx < 5; ++kx) {
            const int cl = lane + 2 * kx;
            // volume operands for both rows, all 4 channel-quads (8 x ds_read_b128)
            float4 v0q[4], v1q[4];
            #pragma unroll
            for (int cq = 0; cq < 4; ++cq) {
                v0q[cq] = lds[cq][r + 0][cl];
                v1q[cq] = lds[cq][r + 1][cl];
            }
            const int wo = (r * 5 + kx) * 16;    // float4 offset within a tap block
            #pragma unroll
            for (int tq = 0; tq < 5; ++tq) {
                const float4* __restrict__ W = wbase + (size_t)tq * 400 + wo;
                #pragma unroll
                for (int cq = 0; cq < 4; ++cq) {
                    const float4 w0 = W[4 * cq + 0], w1 = W[4 * cq + 1];
                    const float4 w2 = W[4 * cq + 2], w3 = W[4 * cq + 3];
                    DOT4Q(acc[tq][0], v0q[cq], w0, w1, w2, w3);
                    DOT4Q(acc[tq][1], v1q[cq], w0, w1, w2, w3);
                }
            }
        }
    }

    // sampling epilogue: lane's pixel; 5 taps x 2 rows x 2 groups
    const int ox = ox0 + lane;
    if (ox < OW) {
        const float* __restrict__ Sb = S + b * HH * WW;
        const float kv = (float)(2 * wid - 4);          // kyt = tn/5 = wid
        #pragma unroll
        for (int tq = 0; tq < 5; ++tq) {
            const int tn = tnb + tq;
            const float ku = (float)(2 * tq - 4);       // kxt = tn%5 = tq
            #pragma unroll
            for (int j = 0; j < 2; ++j) {
                const int oy = oy0 + 2 * j;
                const float4 a = acc[tq][j];
                const float byv = (float)(4 + oy);
                #pragma unroll
                for (int g = 0; g < 2; ++g) {
                    const float dy = g == 0 ? a.x : a.y;
                    const float dx = g == 0 ? a.z : a.w;
                    const float rx = kv + dy;     // pairs with W axis (reference quirk)
                    const float ry = ku + dx;     // pairs with H axis
                    int x0 = (int)rx;             // trunc == astype(int32)
                    int x1 = x0 + 1;
                    int y0 = (int)ry;
                    int y1 = y0 + 1;
                    int x0c = min(max(x0, 0), WW - 1);
                    int x1c = min(max(x1, 0), WW - 1);
                    int y0c = min(max(y0, 0), HH - 1);
                    int y1c = min(max(y1, 0), HH - 1);
                    const float fx0 = (float)x0c, fx1 = (float)x1c;
                    const float fy0 = (float)y0c, fy1 = (float)y1c;
                    const float w0v = (fy1 - ry)  * (fx1 - rx);
                    const float w1v = (fy1 - byv) * (rx - fx0);
                    const float w2v = (ry - fy0)  * (fx1 - rx);
                    const float w3v = (ry - fy0)  * (rx - fx0);
                    const float s00 = Sb[y0c * WW + x0c];
                    const float s01 = Sb[y0c * WW + x1c];
                    const float s10 = Sb[y1c * WW + x0c];
                    const float s11 = Sb[y1c * WW + x1c];
                    out[(size_t)(((b * 2 + g) * OH + oy) * OW + ox) * NTAP + tn]
                        = w0v * s00 + w1v * s01 + w2v * s10 + w3v * s11;
                }
            }
        }
    }
}

extern "C" void kernel_launch(void* const* d_in, const int* in_sizes, int n_in,
                              void* d_out, int out_size, void* d_ws, size_t ws_size,
                              hipStream_t stream) {
    const float* vol   = (const float*)d_in[0];
    const float* w_off = (const float*)d_in[1];
    const float* b_off = (const float*)d_in[2];
    float* out = (float*)d_out;

    float* S   = (float*)d_ws;                                   // 576 KiB
    float* w_t = (float*)((char*)d_ws + 2 * HH * WW * 4);        // 160 KB

    const int nS = 2 * HH * WW;
    const int nW = NTAP * 25 * 16;
    prep_kernel<<<(nS + 255) / 256, 256, 0, stream>>>(vol, S, w_off, (float4*)w_t, nS, nW);

    dim3 grid((OW + TILE - 1) / TILE, 46, 4);   // 6 x 46 x 4 = 1104 blocks
    dconv_kernel<<<grid, 320, 0, stream>>>(vol, w_t, b_off, S, out);
}